// Round 3
// baseline (14585.684 us; speedup 1.0000x reference)
//
#include <hip/hip_runtime.h>

#define T_LEN 1024
#define B_SZ  256
#define D_DIM 64
#define E_DIM 512
#define H_DIM 256

#define SA 552   // flow A-tile LDS stride (bf16 elems)
#define SH 264   // flow hid-tile LDS stride

using short8 = __attribute__((ext_vector_type(8))) short;
using half8  = __attribute__((ext_vector_type(8))) _Float16;
using f32x4  = __attribute__((ext_vector_type(4))) float;

static __device__ __forceinline__ unsigned short f2bf(float v) {
    unsigned u = __float_as_uint(v);
    u += 0x7FFFu + ((u >> 16) & 1u);   // RNE to bf16
    return (unsigned short)(u >> 16);
}
static __device__ __forceinline__ unsigned short f2h(float v) {
    _Float16 h = (_Float16)v;
    unsigned short u;
    __builtin_memcpy(&u, &h, 2);
    return u;
}
static __device__ __forceinline__ float h2f(unsigned short u) {
    _Float16 h;
    __builtin_memcpy(&h, &u, 2);
    return (float)h;
}
static __device__ __forceinline__ float fast_tanh(float x) {
    x = fminf(15.f, fmaxf(-15.f, x));
    float e = __expf(2.f * x);
    return (e - 1.f) / (e + 1.f);
}

// ---- Weight prep ----
// W_inT[l][side][n=256][k=544] bf16, W_stT[l][side][n=64][k=256] bf16,
// W_pack[n=512][k=576] fp16 (k<512: W_res[n][k]; k>=512: W_inp[k-512][n]),
// x_h = fp16 copy of x_sequence.
__global__ void prep_kernel(const float* __restrict__ W_in, const float* __restrict__ W_s,
                            const float* __restrict__ W_t, const float* __restrict__ W_res,
                            const float* __restrict__ W_inp, const float* __restrict__ x_seq,
                            unsigned short* __restrict__ W_inT, unsigned short* __restrict__ W_stT,
                            unsigned short* __restrict__ W_packo, unsigned short* __restrict__ x_h) {
    int idx = blockIdx.x * blockDim.x + threadIdx.x;
    int stride = gridDim.x * blockDim.x;
    const int total1 = 4 * 2 * H_DIM * 544;
    for (int i = idx; i < total1; i += stride) {
        int k = i % 544;
        int n = (i / 544) % H_DIM;
        int side = (i / (544 * H_DIM)) & 1;
        int l = i / (544 * H_DIM * 2);
        int ksrc = (k < 32) ? (side == 0 ? 32 + k : k) : (k + 32);
        W_inT[i] = f2bf(W_in[(l * 576 + ksrc) * H_DIM + n]);
    }
    const int total2 = 4 * 2 * 64 * H_DIM;
    for (int i = idx; i < total2; i += stride) {
        int k = i % H_DIM;
        int n = (i / H_DIM) % 64;
        int side = (i / (H_DIM * 64)) & 1;
        int l = i / (H_DIM * 64 * 2);
        int j = n & 31;
        int d = side ? (32 + j) : j;
        float v = (n < 32) ? W_s[(l * H_DIM + k) * D_DIM + d] : W_t[(l * H_DIM + k) * D_DIM + d];
        W_stT[i] = f2bf(v);
    }
    const int total3 = E_DIM * 576;
    for (int i = idx; i < total3; i += stride) {
        int k = i % 576;
        int n = i / 576;
        float v = (k < E_DIM) ? W_res[n * E_DIM + k] : W_inp[(k - E_DIM) * E_DIM + n];
        W_packo[i] = f2h(v);
    }
    const int total4 = T_LEN * B_SZ * D_DIM;
    for (int i = idx; i < total4; i += stride)
        x_h[i] = f2h(x_seq[i]);
}

// ---- Phase 1: ESN recurrence, weight-resident group-parallel MFMA. ----
// 128 blocks x 128 threads (2 waves). Group g = bid&15 owns batch rows [16g,16g+16);
// member m = bid>>4 owns h-cols [64m,64m+64). All 8 members of a group share bid%8
// (-> same XCD if round-robin mapping holds; correctness does not depend on it).
// B-slice (64x576 fp16) lives in VGPRs (loaded once). Per step: 18 A-frags direct
// from h_buf/x_h global, 36 MFMAs, write slice, one 8-way spin barrier per group.
__launch_bounds__(128)
__global__ void esn_kernel(const unsigned short* __restrict__ x_h,
                           const unsigned short* __restrict__ W_pack,
                           unsigned short* __restrict__ h_store /*bf16 [tc][B][E]*/,
                           unsigned short* __restrict__ h_buf   /*fp16 [2][B][E]*/,
                           unsigned int* __restrict__ ctr,
                           int t0, int tc) {
    const int bid  = blockIdx.x;
    const int g    = bid & 15;
    const int m    = bid >> 4;
    const int tid  = threadIdx.x;
    const int wave = tid >> 6;
    const int lane = tid & 63;
    const int arow = lane & 15;
    const int kq   = lane >> 4;          // 0..3
    const int nb   = m * 64 + wave * 32; // this wave's n-base
    const int r0   = g * 16;             // this group's batch-row base
    const size_t HB = (size_t)B_SZ * E_DIM;
    unsigned int* gctr = ctr + g * 32;   // 128B-separated counters

    // B prologue: the wave's 2 n-frags x 18 k-frags, resident in VGPRs
    half8 bfr[2][18];
    #pragma unroll
    for (int nf = 0; nf < 2; ++nf)
        #pragma unroll
        for (int ks = 0; ks < 18; ++ks)
            bfr[nf][ks] = *reinterpret_cast<const half8*>(
                &W_pack[(size_t)(nb + nf * 16 + arow) * 576 + ks * 32 + kq * 8]);

    const size_t hoff = (size_t)(r0 + arow) * E_DIM + kq * 8;

    for (int tl = 0; tl < tc; ++tl) {
        const int t = t0 + tl;
        const unsigned short* hb_r = h_buf + (size_t)(t & 1) * HB;
        unsigned short*       hb_w = h_buf + (size_t)((t & 1) ^ 1) * HB;

        if (tl == 0) {   // h_store[0] own col-slice (bf16 <- h_buf fp16)
            for (int i = tid; i < 16 * 64; i += 128) {
                int r = i >> 6, n = m * 64 + (i & 63);
                h_store[((size_t)(r0 + r)) * E_DIM + n] = f2bf(h2f(hb_r[(size_t)(r0 + r) * E_DIM + n]));
            }
        }

        // A-frags: issue all 18 upfront (16 h + 2 x)
        half8 af[18];
        #pragma unroll
        for (int ks = 0; ks < 16; ++ks)
            af[ks] = *reinterpret_cast<const half8*>(&hb_r[hoff + ks * 32]);
        {
            const unsigned short* xp = &x_h[((size_t)t * B_SZ + r0 + arow) * D_DIM + kq * 8];
            af[16] = *reinterpret_cast<const half8*>(xp);
            af[17] = *reinterpret_cast<const half8*>(xp + 32);
        }

        f32x4 acc[2][2];
        acc[0][0] = (f32x4){0.f,0.f,0.f,0.f}; acc[0][1] = (f32x4){0.f,0.f,0.f,0.f};
        acc[1][0] = (f32x4){0.f,0.f,0.f,0.f}; acc[1][1] = (f32x4){0.f,0.f,0.f,0.f};
        #pragma unroll
        for (int ks = 0; ks < 18; ++ks) {
            acc[0][ks & 1] = __builtin_amdgcn_mfma_f32_16x16x32_f16(af[ks], bfr[0][ks], acc[0][ks & 1], 0, 0, 0);
            acc[1][ks & 1] = __builtin_amdgcn_mfma_f32_16x16x32_f16(af[ks], bfr[1][ks], acc[1][ks & 1], 0, 0, 0);
        }

        // epilogue: h(t+1) slice -> h_buf (fp16) + h_store (bf16)
        #pragma unroll
        for (int nf = 0; nf < 2; ++nf) {
            const int n = nb + nf * 16 + arow;
            #pragma unroll
            for (int i = 0; i < 4; ++i) {
                const int row = kq * 4 + i;
                float hv = fast_tanh(acc[nf][0][i] + acc[nf][1][i]);
                hb_w[(size_t)(r0 + row) * E_DIM + n] = f2h(hv);
                if (tl + 1 < tc)
                    h_store[((size_t)(tl + 1) * B_SZ + r0 + row) * E_DIM + n] = f2bf(hv);
            }
        }

        // group barrier: writes visible -> arrive -> spin -> acquire
        __threadfence();
        __syncthreads();
        if (tid == 0) {
            __hip_atomic_fetch_add(gctr, 1u, __ATOMIC_RELEASE, __HIP_MEMORY_SCOPE_AGENT);
            const unsigned tgt = 8u * (unsigned)(t + 1);
            while (__hip_atomic_load(gctr, __ATOMIC_ACQUIRE, __HIP_MEMORY_SCOPE_AGENT) < tgt) {}
        }
        __syncthreads();
        (void)__hip_atomic_load(gctr, __ATOMIC_ACQUIRE, __HIP_MEMORY_SCOPE_AGENT);
    }
}

// ---- Phase 2: flow log-likelihood, MFMA bf16 (unchanged, verified). ----
__launch_bounds__(256, 2)
__global__ void flow_kernel(const float* __restrict__ x_seq, const unsigned short* __restrict__ h_store,
                            const unsigned short* __restrict__ W_inT, const unsigned short* __restrict__ W_stT,
                            const float* __restrict__ b_in, const float* __restrict__ b_s,
                            const float* __restrict__ b_t, const float* __restrict__ rescale_w,
                            const int* __restrict__ seq_len, float* __restrict__ ll_part,
                            int t0, int tc) {
    const int tt   = blockIdx.x >> 4;
    const int bt   = blockIdx.x & 15;
    const int tid  = threadIdx.x;
    const int wave = tid >> 6;
    const int lane = tid & 63;

    __shared__ unsigned short abf[32 * SA];
    __shared__ unsigned short hidbf[32 * SH];
    __shared__ float zf[32][D_DIM];
    __shared__ float llacc[32];
    __shared__ float llb[16];
    float* stf = reinterpret_cast<float*>(hidbf);

    if (tid < 16) llb[tid] = 0.f;

    const int r8 = tid >> 3;
    const int c8 = tid & 7;

    for (int s = 0; s < 8; ++s) {
        const int trow = tt * 16 + 2 * s + (r8 >> 4);
        const int brow = bt * 16 + (r8 & 15);
        {
            const float* xp = &x_seq[((size_t)(t0 + trow) * B_SZ + brow) * D_DIM + c8 * 8];
            float4 v0 = *reinterpret_cast<const float4*>(xp);
            float4 v1 = *reinterpret_cast<const float4*>(xp + 4);
            *reinterpret_cast<float4*>(&zf[r8][c8 * 8])     = v0;
            *reinterpret_cast<float4*>(&zf[r8][c8 * 8 + 4]) = v1;
            const unsigned short* hp = &h_store[((size_t)trow * B_SZ + brow) * E_DIM + c8 * 64];
            unsigned short* ap = &abf[r8 * SA + 32 + c8 * 64];
            #pragma unroll
            for (int q = 0; q < 8; ++q)
                *reinterpret_cast<uint4*>(ap + q * 8) = *reinterpret_cast<const uint4*>(hp + q * 8);
        }
        if (tid < 32) llacc[tid] = 0.f;
        __syncthreads();

        for (int stage = 0; stage < 8; ++stage) {
            const int l = 3 - (stage >> 1);
            const int side = stage & 1;
            {
                #pragma unroll
                for (int q = 0; q < 4; ++q) {
                    int k = c8 * 4 + q;
                    int d = side ? k : (32 + k);
                    abf[r8 * SA + k] = f2bf(zf[r8][d]);
                }
            }
            __syncthreads();

            const unsigned short* Wl = W_inT + (size_t)(l * 2 + side) * H_DIM * 544;
            f32x4 acc[2][4];
            #pragma unroll
            for (int mt = 0; mt < 2; ++mt)
                #pragma unroll
                for (int nt = 0; nt < 4; ++nt)
                    acc[mt][nt] = (f32x4){0.f, 0.f, 0.f, 0.f};
            const int aoff  = (lane & 15) * SA + 8 * (lane >> 4);
            const int koff  = 8 * (lane >> 4);
            for (int ks = 0; ks < 17; ++ks) {
                const int k0 = ks * 32;
                short8 a0 = *reinterpret_cast<const short8*>(&abf[aoff + k0]);
                short8 a1 = *reinterpret_cast<const short8*>(&abf[16 * SA + aoff + k0]);
                #pragma unroll
                for (int nt = 0; nt < 4; ++nt) {
                    const int n = wave * 64 + nt * 16 + (lane & 15);
                    short8 bb = *reinterpret_cast<const short8*>(&Wl[(size_t)n * 544 + k0 + koff]);
                    acc[0][nt] = __builtin_amdgcn_mfma_f32_16x16x32_bf16(a0, bb, acc[0][nt], 0, 0, 0);
                    acc[1][nt] = __builtin_amdgcn_mfma_f32_16x16x32_bf16(a1, bb, acc[1][nt], 0, 0, 0);
                }
            }
            #pragma unroll
            for (int mt = 0; mt < 2; ++mt)
                #pragma unroll
                for (int nt = 0; nt < 4; ++nt) {
                    const int n = wave * 64 + nt * 16 + (lane & 15);
                    const float bias = b_in[l * H_DIM + n];
                    #pragma unroll
                    for (int i = 0; i < 4; ++i) {
                        const int row = mt * 16 + (lane >> 4) * 4 + i;
                        hidbf[row * SH + n] = f2bf(fast_tanh(acc[mt][nt][i] + bias));
                    }
                }
            __syncthreads();

            const unsigned short* Wst = W_stT + (size_t)(l * 2 + side) * 64 * H_DIM;
            f32x4 acc2[2];
            acc2[0] = (f32x4){0.f,0.f,0.f,0.f};
            acc2[1] = (f32x4){0.f,0.f,0.f,0.f};
            const int hoff = (lane & 15) * SH + 8 * (lane >> 4);
            const int nst  = wave * 16 + (lane & 15);
            const unsigned short* Wstn = &Wst[(size_t)nst * H_DIM + 8 * (lane >> 4)];
            #pragma unroll
            for (int ks = 0; ks < 8; ++ks) {
                const int k0 = ks * 32;
                short8 a0 = *reinterpret_cast<const short8*>(&hidbf[hoff + k0]);
                short8 a1 = *reinterpret_cast<const short8*>(&hidbf[16 * SH + hoff + k0]);
                short8 bb = *reinterpret_cast<const short8*>(&Wstn[k0]);
                acc2[0] = __builtin_amdgcn_mfma_f32_16x16x32_bf16(a0, bb, acc2[0], 0, 0, 0);
                acc2[1] = __builtin_amdgcn_mfma_f32_16x16x32_bf16(a1, bb, acc2[1], 0, 0, 0);
            }
            __syncthreads();
            {
                const int j = nst & 31;
                const int d = side ? (32 + j) : j;
                const bool is_s = (nst < 32);
                const float bias = is_s ? b_s[l * D_DIM + d] : b_t[l * D_DIM + d];
                const float rs = rescale_w[d];
                #pragma unroll
                for (int mt = 0; mt < 2; ++mt)
                    #pragma unroll
                    for (int i = 0; i < 4; ++i) {
                        const int row = mt * 16 + (lane >> 4) * 4 + i;
                        const float v = acc2[mt][i] + bias;
                        stf[row * 64 + nst] = is_s ? (fast_tanh(v) * rs) : v;
                    }
            }
            __syncthreads();
            {
                #pragma unroll
                for (int q = 0; q < 4; ++q) {
                    const int j = c8 * 4 + q;
                    const int d = side ? (32 + j) : j;
                    const float sv = stf[r8 * 64 + j];
                    const float iv = stf[r8 * 64 + 32 + j];
                    zf[r8][d] = (zf[r8][d] - iv) * __expf(-sv);
                }
            }
            if (tid < 32) {
                float ssum = 0.f;
                #pragma unroll
                for (int j = 0; j < 32; ++j) ssum += stf[tid * 64 + j];
                llacc[tid] -= ssum;
            }
            __syncthreads();
        } // stage

        if (tid < 32) {
            float zsum = 0.f;
            #pragma unroll
            for (int d = 0; d < D_DIM; ++d) { float z = zf[tid][d]; zsum += z * z; }
            float ll = llacc[tid] - 0.5f * zsum - 58.812066125f;
            const int tg = t0 + tt * 16 + 2 * s + (tid >> 4);
            const int bg = bt * 16 + (tid & 15);
            llacc[tid] = (tg < seq_len[bg]) ? ll : 0.f;
        }
        __syncthreads();
        if (tid < 16) llb[tid] += llacc[tid] + llacc[16 + tid];
        __syncthreads();
    } // subtiles

    if (tid < 16)
        ll_part[((t0 >> 4) + tt) * B_SZ + bt * 16 + tid] = llb[tid];
}

__global__ void reduce_kernel(const float* __restrict__ ll_part, float* __restrict__ out) {
    int b = threadIdx.x;
    float s = 0.f;
    #pragma unroll
    for (int tt = 0; tt < T_LEN / 16; ++tt) s += ll_part[tt * B_SZ + b];
    out[b] = s;
}

extern "C" void kernel_launch(void* const* d_in, const int* in_sizes, int n_in,
                              void* d_out, int out_size, void* d_ws, size_t ws_size,
                              hipStream_t stream) {
    const float* x_seq   = (const float*)d_in[0];
    const int*   seqlen  = (const int*)d_in[1];
    const float* W_in    = (const float*)d_in[3];
    const float* b_in    = (const float*)d_in[4];
    const float* W_s     = (const float*)d_in[5];
    const float* b_s     = (const float*)d_in[6];
    const float* W_t     = (const float*)d_in[7];
    const float* b_t     = (const float*)d_in[8];
    const float* rescale = (const float*)d_in[9];
    const float* W_res   = (const float*)d_in[10];
    const float* W_inp   = (const float*)d_in[11];

    char* ws = (char*)d_ws;
    size_t off = 0;
    unsigned short* W_inT  = (unsigned short*)(ws + off); off += (size_t)4 * 2 * H_DIM * 544 * 2;
    unsigned short* W_stT  = (unsigned short*)(ws + off); off += (size_t)4 * 2 * 64 * H_DIM * 2;
    unsigned short* W_pack = (unsigned short*)(ws + off); off += (size_t)E_DIM * 576 * 2;
    unsigned short* x_h    = (unsigned short*)(ws + off); off += (size_t)T_LEN * B_SZ * D_DIM * 2;
    unsigned short* h_buf  = (unsigned short*)(ws + off); off += (size_t)2 * B_SZ * E_DIM * 2;
    float* ll_part = (float*)(ws + off); off += (size_t)(T_LEN / 16) * B_SZ * 4;
    unsigned int* ctr = (unsigned int*)(ws + off); off += (size_t)16 * 32 * 4;
    unsigned short* h_store = (unsigned short*)(ws + off);

    size_t per_t = (size_t)B_SZ * E_DIM * 2;
    size_t rem = (ws_size > off) ? (ws_size - off) : 0;
    long long tcl = (long long)(rem / per_t);
    int tc = (int)((tcl > T_LEN) ? T_LEN : tcl);
    tc &= ~15;
    if (tc < 16) tc = 16;

    hipMemsetAsync(h_buf, 0, (size_t)2 * B_SZ * E_DIM * 2, stream);
    hipMemsetAsync(ctr, 0, (size_t)16 * 32 * 4, stream);

    prep_kernel<<<2048, 256, 0, stream>>>(W_in, W_s, W_t, W_res, W_inp, x_seq,
                                          W_inT, W_stT, W_pack, x_h);
    for (int t0 = 0; t0 < T_LEN; t0 += tc) {
        int cur = T_LEN - t0; if (cur > tc) cur = tc;
        esn_kernel<<<128, 128, 0, stream>>>(x_h, W_pack, h_store, h_buf, ctr, t0, cur);
        flow_kernel<<<(cur / 16) * 16, 256, 0, stream>>>(x_seq, h_store, W_inT, W_stT, b_in, b_s, b_t,
                                                         rescale, seqlen, ll_part, t0, cur);
    }
    reduce_kernel<<<1, B_SZ, 0, stream>>>(ll_part, (float*)d_out);
}

// Round 5
// 5195.861 us; speedup vs baseline: 2.8072x; 2.8072x over previous
//
#include <hip/hip_runtime.h>

#define T_LEN 1024
#define B_SZ  256
#define D_DIM 64
#define E_DIM 512
#define H_DIM 256

#define SA 552   // flow A-tile LDS stride (bf16 elems)
#define SH 264   // flow hid-tile LDS stride
#define KW 584   // esn LDS row stride (fp16 elems): 576+8 pad

using short8 = __attribute__((ext_vector_type(8))) short;
using half8  = __attribute__((ext_vector_type(8))) _Float16;
using f32x4  = __attribute__((ext_vector_type(4))) float;

static __device__ __forceinline__ unsigned short f2bf(float v) {
    unsigned u = __float_as_uint(v);
    u += 0x7FFFu + ((u >> 16) & 1u);   // RNE to bf16
    return (unsigned short)(u >> 16);
}
static __device__ __forceinline__ unsigned short f2h(float v) {
    _Float16 h = (_Float16)v;
    unsigned short u;
    __builtin_memcpy(&u, &h, 2);
    return u;
}
static __device__ __forceinline__ float h2f(unsigned short u) {
    _Float16 h;
    __builtin_memcpy(&h, &u, 2);
    return (float)h;
}
static __device__ __forceinline__ float fast_tanh(float x) {
    x = fminf(15.f, fmaxf(-15.f, x));
    float e = __expf(2.f * x);
    return (e - 1.f) / (e + 1.f);
}

// ---- Weight prep ----
__global__ void prep_kernel(const float* __restrict__ W_in, const float* __restrict__ W_s,
                            const float* __restrict__ W_t, const float* __restrict__ W_res,
                            const float* __restrict__ W_inp, const float* __restrict__ x_seq,
                            unsigned short* __restrict__ W_inT, unsigned short* __restrict__ W_stT,
                            unsigned short* __restrict__ W_packo, unsigned short* __restrict__ x_h) {
    int idx = blockIdx.x * blockDim.x + threadIdx.x;
    int stride = gridDim.x * blockDim.x;
    const int total1 = 4 * 2 * H_DIM * 544;
    for (int i = idx; i < total1; i += stride) {
        int k = i % 544;
        int n = (i / 544) % H_DIM;
        int side = (i / (544 * H_DIM)) & 1;
        int l = i / (544 * H_DIM * 2);
        int ksrc = (k < 32) ? (side == 0 ? 32 + k : k) : (k + 32);
        W_inT[i] = f2bf(W_in[(l * 576 + ksrc) * H_DIM + n]);
    }
    const int total2 = 4 * 2 * 64 * H_DIM;
    for (int i = idx; i < total2; i += stride) {
        int k = i % H_DIM;
        int n = (i / H_DIM) % 64;
        int side = (i / (H_DIM * 64)) & 1;
        int l = i / (H_DIM * 64 * 2);
        int j = n & 31;
        int d = side ? (32 + j) : j;
        float v = (n < 32) ? W_s[(l * H_DIM + k) * D_DIM + d] : W_t[(l * H_DIM + k) * D_DIM + d];
        W_stT[i] = f2bf(v);
    }
    const int total3 = E_DIM * 576;
    for (int i = idx; i < total3; i += stride) {
        int k = i % 576;
        int n = i / 576;
        float v = (k < E_DIM) ? W_res[n * E_DIM + k] : W_inp[(k - E_DIM) * E_DIM + n];
        W_packo[i] = f2h(v);
    }
    const int total4 = T_LEN * B_SZ * D_DIM;
    for (int i = idx; i < total4; i += stride)
        x_h[i] = f2h(x_seq[i]);
}

// ---- Phase 1: ESN recurrence, W sharded into LDS across 8-block groups. ----
// 128 blocks x 256 threads. Group g = bid&15 owns batch rows [16g,16g+16);
// member m = bid>>4 owns h-cols [64m,64m+64) with its W-slice in LDS (74.8 KB).
// Per step: read full h(t) (16 KB) from LLC (relaxed system atomics, NO fences),
// 18 MFMAs/wave, write own 2 KB slice to LLC, one relaxed atomicAdd barrier.
// Placement-independent: all coherence via device-scope atomics / LLC path.
__launch_bounds__(256, 1)
__global__ void esn_kernel(const unsigned short* __restrict__ x_h,
                           const unsigned short* __restrict__ W_pack,
                           unsigned short* __restrict__ h_store /*bf16 [tc][B][E]*/,
                           unsigned short* __restrict__ h_buf   /*fp16 [2][B][E]*/,
                           unsigned int* __restrict__ ctr,
                           int t0, int tc) {
    const int bid  = blockIdx.x;
    const int g    = bid & 15;
    const int m    = bid >> 4;
    const int tid  = threadIdx.x;
    const int wave = tid >> 6;
    const int lane = tid & 63;
    const int arow = lane & 15;
    const int kq   = lane >> 4;
    const int r0   = g * 16;
    const int n0   = m * 64;
    const size_t HB = (size_t)B_SZ * E_DIM;
    unsigned int* gctr = ctr + g * 32;

    extern __shared__ unsigned short smem[];
    unsigned short* Wl = smem;            // [64][KW] W-slice
    unsigned short* hA = smem + 64 * KW;  // [16][KW] = [h(512) | x(64)]

    // W-slice -> LDS (once)
    for (int i = tid; i < 64 * 72; i += 256) {
        int row = i / 72, c8 = (i % 72) * 8;
        *reinterpret_cast<uint4*>(&Wl[row * KW + c8]) =
            *reinterpret_cast<const uint4*>(&W_pack[(size_t)(n0 + row) * 576 + c8]);
    }

    const int hr_row = tid >> 4;          // 0..15
    const int hr_n   = (tid & 15) * 32;   // 0..480
    const int xr = tid >> 4, xc = (tid & 15) * 4;

    for (int tl = 0; tl < tc; ++tl) {
        const int t = t0 + tl;
        const unsigned short* hb_r = h_buf + (size_t)(t & 1) * HB;
        unsigned short*       hb_w = h_buf + (size_t)((t & 1) ^ 1) * HB;

        // x(t) (plain cached load) - overlaps the spin
        uint2 xv = *reinterpret_cast<const uint2*>(
            &x_h[((size_t)t * B_SZ + r0 + xr) * D_DIM + xc]);

        // spin until all 8 members finished step t-1 (ctr is monotonic, 8 per step)
        if (tid == 0) {
            while (__hip_atomic_fetch_add(gctr, 0u, __ATOMIC_RELAXED,
                                          __HIP_MEMORY_SCOPE_AGENT) < 8u * (unsigned)t)
                __builtin_amdgcn_s_sleep(1);
        }
        __syncthreads();
        asm volatile("" ::: "memory");

        // h(t): 64 B/thread from LLC (relaxed system-scope loads, no cache maint.)
        const unsigned long long* hp = reinterpret_cast<const unsigned long long*>(
            &hb_r[(size_t)(r0 + hr_row) * E_DIM + hr_n]);
        unsigned long long hv0 = __hip_atomic_load(hp + 0, __ATOMIC_RELAXED, __HIP_MEMORY_SCOPE_SYSTEM);
        unsigned long long hv1 = __hip_atomic_load(hp + 1, __ATOMIC_RELAXED, __HIP_MEMORY_SCOPE_SYSTEM);
        unsigned long long hv2 = __hip_atomic_load(hp + 2, __ATOMIC_RELAXED, __HIP_MEMORY_SCOPE_SYSTEM);
        unsigned long long hv3 = __hip_atomic_load(hp + 3, __ATOMIC_RELAXED, __HIP_MEMORY_SCOPE_SYSTEM);
        unsigned long long hv4 = __hip_atomic_load(hp + 4, __ATOMIC_RELAXED, __HIP_MEMORY_SCOPE_SYSTEM);
        unsigned long long hv5 = __hip_atomic_load(hp + 5, __ATOMIC_RELAXED, __HIP_MEMORY_SCOPE_SYSTEM);
        unsigned long long hv6 = __hip_atomic_load(hp + 6, __ATOMIC_RELAXED, __HIP_MEMORY_SCOPE_SYSTEM);
        unsigned long long hv7 = __hip_atomic_load(hp + 7, __ATOMIC_RELAXED, __HIP_MEMORY_SCOPE_SYSTEM);

        unsigned long long* dp = reinterpret_cast<unsigned long long*>(&hA[hr_row * KW + hr_n]);
        dp[0] = hv0; dp[1] = hv1; dp[2] = hv2; dp[3] = hv3;
        dp[4] = hv4; dp[5] = hv5; dp[6] = hv6; dp[7] = hv7;
        *reinterpret_cast<uint2*>(&hA[xr * KW + E_DIM + xc]) = xv;
        __syncthreads();

        if (tl == 0) {   // h_store[0] = bf16(h(t0)) straight from the regs
            unsigned long long hs[8] = {hv0, hv1, hv2, hv3, hv4, hv5, hv6, hv7};
            #pragma unroll
            for (int j = 0; j < 8; ++j) {
                unsigned short o[4];
                #pragma unroll
                for (int q = 0; q < 4; ++q)
                    o[q] = f2bf(h2f((unsigned short)(hs[j] >> (16 * q))));
                unsigned long long pk;
                __builtin_memcpy(&pk, o, 8);
                *reinterpret_cast<unsigned long long*>(
                    &h_store[(size_t)(r0 + hr_row) * E_DIM + hr_n + j * 4]) = pk;
            }
        }

        // MFMA: wave w -> Ntile w (16 cols), K=576
        f32x4 accA = (f32x4){0.f, 0.f, 0.f, 0.f};
        f32x4 accB = (f32x4){0.f, 0.f, 0.f, 0.f};
        #pragma unroll
        for (int ks = 0; ks < 18; ++ks) {
            half8 a = *reinterpret_cast<const half8*>(&hA[arow * KW + ks * 32 + kq * 8]);
            half8 b = *reinterpret_cast<const half8*>(&Wl[(wave * 16 + arow) * KW + ks * 32 + kq * 8]);
            if (ks & 1) accB = __builtin_amdgcn_mfma_f32_16x16x32_f16(a, b, accB, 0, 0, 0);
            else        accA = __builtin_amdgcn_mfma_f32_16x16x32_f16(a, b, accA, 0, 0, 0);
        }
        f32x4 acc = accA + accB;

        const int ncol = n0 + wave * 16 + arow;
        #pragma unroll
        for (int i = 0; i < 4; ++i) {
            const int row = r0 + kq * 4 + i;
            float hvf = fast_tanh(acc[i]);
            __hip_atomic_store(&hb_w[(size_t)row * E_DIM + ncol], f2h(hvf),
                               __ATOMIC_RELAXED, __HIP_MEMORY_SCOPE_SYSTEM);
            if (tl + 1 < tc)
                h_store[((size_t)(tl + 1) * B_SZ + row) * E_DIM + ncol] = f2bf(hvf);
        }

        asm volatile("s_waitcnt vmcnt(0)" ::: "memory");
        __syncthreads();
        if (tid == 0)
            __hip_atomic_fetch_add(gctr, 1u, __ATOMIC_RELAXED, __HIP_MEMORY_SCOPE_AGENT);
    }
}

// ---- Phase 2: flow log-likelihood (verified structure; hid k-loop now B-prefetched). ----
__launch_bounds__(256, 2)
__global__ void flow_kernel(const float* __restrict__ x_seq, const unsigned short* __restrict__ h_store,
                            const unsigned short* __restrict__ W_inT, const unsigned short* __restrict__ W_stT,
                            const float* __restrict__ b_in, const float* __restrict__ b_s,
                            const float* __restrict__ b_t, const float* __restrict__ rescale_w,
                            const int* __restrict__ seq_len, float* __restrict__ ll_part,
                            int t0, int tc) {
    const int tt   = blockIdx.x >> 4;
    const int bt   = blockIdx.x & 15;
    const int tid  = threadIdx.x;
    const int wave = tid >> 6;
    const int lane = tid & 63;

    __shared__ unsigned short abf[32 * SA];
    __shared__ unsigned short hidbf[32 * SH];
    __shared__ float zf[32][D_DIM];
    __shared__ float llacc[32];
    __shared__ float llb[16];
    float* stf = reinterpret_cast<float*>(hidbf);

    if (tid < 16) llb[tid] = 0.f;

    const int r8 = tid >> 3;
    const int c8 = tid & 7;

    for (int s = 0; s < 8; ++s) {
        const int trow = tt * 16 + 2 * s + (r8 >> 4);
        const int brow = bt * 16 + (r8 & 15);
        {
            const float* xp = &x_seq[((size_t)(t0 + trow) * B_SZ + brow) * D_DIM + c8 * 8];
            float4 v0 = *reinterpret_cast<const float4*>(xp);
            float4 v1 = *reinterpret_cast<const float4*>(xp + 4);
            *reinterpret_cast<float4*>(&zf[r8][c8 * 8])     = v0;
            *reinterpret_cast<float4*>(&zf[r8][c8 * 8 + 4]) = v1;
            const unsigned short* hp = &h_store[((size_t)trow * B_SZ + brow) * E_DIM + c8 * 64];
            unsigned short* ap = &abf[r8 * SA + 32 + c8 * 64];
            #pragma unroll
            for (int q = 0; q < 8; ++q)
                *reinterpret_cast<uint4*>(ap + q * 8) = *reinterpret_cast<const uint4*>(hp + q * 8);
        }
        if (tid < 32) llacc[tid] = 0.f;
        __syncthreads();

        for (int stage = 0; stage < 8; ++stage) {
            const int l = 3 - (stage >> 1);
            const int side = stage & 1;
            {
                #pragma unroll
                for (int q = 0; q < 4; ++q) {
                    int k = c8 * 4 + q;
                    int d = side ? k : (32 + k);
                    abf[r8 * SA + k] = f2bf(zf[r8][d]);
                }
            }
            __syncthreads();

            const unsigned short* Wl = W_inT + (size_t)(l * 2 + side) * H_DIM * 544;
            f32x4 acc[2][4];
            #pragma unroll
            for (int mt = 0; mt < 2; ++mt)
                #pragma unroll
                for (int nt = 0; nt < 4; ++nt)
                    acc[mt][nt] = (f32x4){0.f, 0.f, 0.f, 0.f};
            const int aoff  = (lane & 15) * SA + 8 * (lane >> 4);
            const int koff  = 8 * (lane >> 4);
            const unsigned short* wptr[4];
            short8 bcur[4], bnext[4];
            #pragma unroll
            for (int nt = 0; nt < 4; ++nt) {
                const int n = wave * 64 + nt * 16 + (lane & 15);
                wptr[nt] = &Wl[(size_t)n * 544 + koff];
                bcur[nt] = *reinterpret_cast<const short8*>(wptr[nt]);
            }
            #pragma unroll
            for (int ks = 0; ks < 17; ++ks) {
                const int k0 = ks * 32;
                short8 a0 = *reinterpret_cast<const short8*>(&abf[aoff + k0]);
                short8 a1 = *reinterpret_cast<const short8*>(&abf[16 * SA + aoff + k0]);
                if (ks < 16) {
                    #pragma unroll
                    for (int nt = 0; nt < 4; ++nt)
                        bnext[nt] = *reinterpret_cast<const short8*>(wptr[nt] + k0 + 32);
                }
                #pragma unroll
                for (int nt = 0; nt < 4; ++nt) {
                    acc[0][nt] = __builtin_amdgcn_mfma_f32_16x16x32_bf16(a0, bcur[nt], acc[0][nt], 0, 0, 0);
                    acc[1][nt] = __builtin_amdgcn_mfma_f32_16x16x32_bf16(a1, bcur[nt], acc[1][nt], 0, 0, 0);
                }
                if (ks < 16) {
                    #pragma unroll
                    for (int nt = 0; nt < 4; ++nt) bcur[nt] = bnext[nt];
                }
            }
            #pragma unroll
            for (int mt = 0; mt < 2; ++mt)
                #pragma unroll
                for (int nt = 0; nt < 4; ++nt) {
                    const int n = wave * 64 + nt * 16 + (lane & 15);
                    const float bias = b_in[l * H_DIM + n];
                    #pragma unroll
                    for (int i = 0; i < 4; ++i) {
                        const int row = mt * 16 + (lane >> 4) * 4 + i;
                        hidbf[row * SH + n] = f2bf(fast_tanh(acc[mt][nt][i] + bias));
                    }
                }
            __syncthreads();

            const unsigned short* Wst = W_stT + (size_t)(l * 2 + side) * 64 * H_DIM;
            f32x4 acc2[2];
            acc2[0] = (f32x4){0.f,0.f,0.f,0.f};
            acc2[1] = (f32x4){0.f,0.f,0.f,0.f};
            const int hoff = (lane & 15) * SH + 8 * (lane >> 4);
            const int nst  = wave * 16 + (lane & 15);
            const unsigned short* Wstn = &Wst[(size_t)nst * H_DIM + 8 * (lane >> 4)];
            #pragma unroll
            for (int ks = 0; ks < 8; ++ks) {
                const int k0 = ks * 32;
                short8 a0 = *reinterpret_cast<const short8*>(&hidbf[hoff + k0]);
                short8 a1 = *reinterpret_cast<const short8*>(&hidbf[16 * SH + hoff + k0]);
                short8 bb = *reinterpret_cast<const short8*>(&Wstn[k0]);
                acc2[0] = __builtin_amdgcn_mfma_f32_16x16x32_bf16(a0, bb, acc2[0], 0, 0, 0);
                acc2[1] = __builtin_amdgcn_mfma_f32_16x16x32_bf16(a1, bb, acc2[1], 0, 0, 0);
            }
            __syncthreads();
            {
                const int j = nst & 31;
                const int d = side ? (32 + j) : j;
                const bool is_s = (nst < 32);
                const float bias = is_s ? b_s[l * D_DIM + d] : b_t[l * D_DIM + d];
                const float rs = rescale_w[d];
                #pragma unroll
                for (int mt = 0; mt < 2; ++mt)
                    #pragma unroll
                    for (int i = 0; i < 4; ++i) {
                        const int row = mt * 16 + (lane >> 4) * 4 + i;
                        const float v = acc2[mt][i] + bias;
                        stf[row * 64 + nst] = is_s ? (fast_tanh(v) * rs) : v;
                    }
            }
            __syncthreads();
            {
                #pragma unroll
                for (int q = 0; q < 4; ++q) {
                    const int j = c8 * 4 + q;
                    const int d = side ? (32 + j) : j;
                    const float sv = stf[r8 * 64 + j];
                    const float iv = stf[r8 * 64 + 32 + j];
                    zf[r8][d] = (zf[r8][d] - iv) * __expf(-sv);
                }
            }
            if (tid < 32) {
                float ssum = 0.f;
                #pragma unroll
                for (int j = 0; j < 32; ++j) ssum += stf[tid * 64 + j];
                llacc[tid] -= ssum;
            }
            __syncthreads();
        } // stage

        if (tid < 32) {
            float zsum = 0.f;
            #pragma unroll
            for (int d = 0; d < D_DIM; ++d) { float z = zf[tid][d]; zsum += z * z; }
            float ll = llacc[tid] - 0.5f * zsum - 58.812066125f;
            const int tg = t0 + tt * 16 + 2 * s + (tid >> 4);
            const int bg = bt * 16 + (tid & 15);
            llacc[tid] = (tg < seq_len[bg]) ? ll : 0.f;
        }
        __syncthreads();
        if (tid < 16) llb[tid] += llacc[tid] + llacc[16 + tid];
        __syncthreads();
    } // subtiles

    if (tid < 16)
        ll_part[((t0 >> 4) + tt) * B_SZ + bt * 16 + tid] = llb[tid];
}

__global__ void reduce_kernel(const float* __restrict__ ll_part, float* __restrict__ out) {
    int b = threadIdx.x;
    float s = 0.f;
    #pragma unroll
    for (int tt = 0; tt < T_LEN / 16; ++tt) s += ll_part[tt * B_SZ + b];
    out[b] = s;
}

extern "C" void kernel_launch(void* const* d_in, const int* in_sizes, int n_in,
                              void* d_out, int out_size, void* d_ws, size_t ws_size,
                              hipStream_t stream) {
    const float* x_seq   = (const float*)d_in[0];
    const int*   seqlen  = (const int*)d_in[1];
    const float* W_in    = (const float*)d_in[3];
    const float* b_in    = (const float*)d_in[4];
    const float* W_s     = (const float*)d_in[5];
    const float* b_s     = (const float*)d_in[6];
    const float* W_t     = (const float*)d_in[7];
    const float* b_t     = (const float*)d_in[8];
    const float* rescale = (const float*)d_in[9];
    const float* W_res   = (const float*)d_in[10];
    const float* W_inp   = (const float*)d_in[11];

    char* ws = (char*)d_ws;
    size_t off = 0;
    unsigned short* W_inT  = (unsigned short*)(ws + off); off += (size_t)4 * 2 * H_DIM * 544 * 2;
    unsigned short* W_stT  = (unsigned short*)(ws + off); off += (size_t)4 * 2 * 64 * H_DIM * 2;
    unsigned short* W_pack = (unsigned short*)(ws + off); off += (size_t)E_DIM * 576 * 2;
    unsigned short* x_h    = (unsigned short*)(ws + off); off += (size_t)T_LEN * B_SZ * D_DIM * 2;
    float* ll_part = (float*)(ws + off); off += (size_t)(T_LEN / 16) * B_SZ * 4;
    unsigned short* h_buf  = (unsigned short*)(ws + off); off += (size_t)2 * B_SZ * E_DIM * 2;
    unsigned int* ctr = (unsigned int*)(ws + off); off += (size_t)16 * 32 * 4;
    unsigned short* h_store = (unsigned short*)(ws + off);

    size_t per_t = (size_t)B_SZ * E_DIM * 2;
    size_t rem = (ws_size > off) ? (ws_size - off) : 0;
    long long tcl = (long long)(rem / per_t);
    int tc = (int)((tcl > T_LEN) ? T_LEN : tcl);
    tc &= ~15;
    if (tc < 16) tc = 16;

    hipMemsetAsync(h_buf, 0, (size_t)2 * B_SZ * E_DIM * 2, stream);
    hipMemsetAsync(ctr, 0, (size_t)16 * 32 * 4, stream);

    prep_kernel<<<2048, 256, 0, stream>>>(W_in, W_s, W_t, W_res, W_inp, x_seq,
                                          W_inT, W_stT, W_pack, x_h);
    const int lds_bytes = (64 + 16) * KW * 2;   // 93,440 B: W-slice + hA
    for (int t0 = 0; t0 < T_LEN; t0 += tc) {
        int cur = T_LEN - t0; if (cur > tc) cur = tc;
        esn_kernel<<<128, 256, lds_bytes, stream>>>(x_h, W_pack, h_store, h_buf, ctr, t0, cur);
        flow_kernel<<<(cur / 16) * 16, 256, 0, stream>>>(x_seq, h_store, W_inT, W_stT, b_in, b_s, b_t,
                                                         rescale, seqlen, ll_part, t0, cur);
    }
    reduce_kernel<<<1, B_SZ, 0, stream>>>(ll_part, (float*)d_out);
}